// Round 1
// baseline (1819.083 us; speedup 1.0000x reference)
//
#include <hip/hip_runtime.h>

#define DD 32   // node/output dim
#define HH 64   // psi hidden
// PSI_IN = 5*32 = 160

// Thread-per-edge fp32 MLP. Weights read wave-uniformly (s_load path),
// acc[64] in VGPRs, LDS only for dynamic-k staging of per-thread rows.
// LDS: 128*33*4 + 128*65*4 = 50176 B (stride 33/65 == 1 mod 32 -> conflict-free).
__global__ __launch_bounds__(128, 2) void edge_kernel(
    const float* __restrict__ h_d, const float* __restrict__ h_s,
    const float* __restrict__ ef,
    const int* __restrict__ snd, const int* __restrict__ rcv,
    const float* __restrict__ w0, const float* __restrict__ b0,
    const float* __restrict__ w1, const float* __restrict__ b1,
    const float* __restrict__ w2, const float* __restrict__ b2,
    float* __restrict__ agg, int E)
{
    __shared__ float pbuf[128][33];
    __shared__ float xbuf[128][65];

    const int tid = threadIdx.x;
    const int e = blockIdx.x * 128 + tid;
    const bool valid = (e < E);
    const int ec = valid ? e : 0;
    const int s_i = snd[ec];
    const int r_i = rcv[ec];

    // ---------------- L0: acc[h] = b0[h] + sum_k psi_in[k] * w0[k][h] ----------------
    float acc[HH];
    #pragma unroll
    for (int h = 0; h < HH; ++h) acc[h] = b0[h];

    #pragma unroll
    for (int p = 0; p < 5; ++p) {
        const float* src = (p == 0) ? h_s + (size_t)s_i * DD
                         : (p == 1) ? h_s + (size_t)r_i * DD
                         : (p == 2) ? h_d + (size_t)s_i * DD
                         : (p == 3) ? h_d + (size_t)r_i * DD
                         :            ef  + (size_t)ec  * DD;
        // stage 32 floats of this psi_in chunk (vector global loads, scalar LDS writes)
        #pragma unroll
        for (int i = 0; i < 8; ++i) {
            const float4 v = reinterpret_cast<const float4*>(src)[i];
            pbuf[tid][4 * i + 0] = v.x;
            pbuf[tid][4 * i + 1] = v.y;
            pbuf[tid][4 * i + 2] = v.z;
            pbuf[tid][4 * i + 3] = v.w;
        }
        #pragma unroll 4
        for (int k = 0; k < 32; ++k) {
            const float xk = pbuf[tid][k];
            const float* wrow = w0 + (size_t)(p * 32 + k) * HH;  // wave-uniform row
            #pragma unroll
            for (int h = 0; h < HH; ++h) acc[h] = fmaf(xk, wrow[h], acc[h]);
        }
    }

    // x0 = relu(acc) -> LDS (needed with dynamic index in L1)
    #pragma unroll
    for (int h = 0; h < HH; ++h) xbuf[tid][h] = fmaxf(acc[h], 0.0f);

    // ---------------- L1 + L2 fused: psiacc[d] = b2[d] + sum_j relu(x1[j]) * w2[j][d] ----------------
    float psiacc[DD];
    #pragma unroll
    for (int d = 0; d < DD; ++d) psiacc[d] = b2[d];

    for (int jc = 0; jc < 4; ++jc) {
        float x1c[16];
        #pragma unroll
        for (int j = 0; j < 16; ++j) x1c[j] = b1[jc * 16 + j];
        #pragma unroll 4
        for (int k = 0; k < HH; ++k) {
            const float xk = xbuf[tid][k];
            const float* wrow = w1 + (size_t)k * HH + jc * 16;   // wave-uniform
            #pragma unroll
            for (int j = 0; j < 16; ++j) x1c[j] = fmaf(xk, wrow[j], x1c[j]);
        }
        #pragma unroll
        for (int j = 0; j < 16; ++j) {
            const float v = fmaxf(x1c[j], 0.0f);
            const float* w2row = w2 + (size_t)(jc * 16 + j) * DD; // wave-uniform
            #pragma unroll
            for (int d = 0; d < DD; ++d) psiacc[d] = fmaf(v, w2row[d], psiacc[d]);
        }
    }

    // ---------------- epilogue: s_ij = relu(psi) * (h_dj - h_di); scatter-add ----------------
    if (valid) {
        const float* hdi = h_d + (size_t)s_i * DD;
        const float* hdj = h_d + (size_t)r_i * DD;
        float* arow = agg + (size_t)r_i * DD;
        #pragma unroll
        for (int d = 0; d < DD; ++d) {
            const float po = fmaxf(psiacc[d], 0.0f);
            const float sij = po * (hdj[d] - hdi[d]);
            atomicAdd(arow + d, sij);
        }
    }
}

// out[n][d] = h_d_prev[n][d] + sum_k agg[n][k] * W[k][d]
__global__ __launch_bounds__(256) void out_kernel(
    const float* __restrict__ h_d, const float* __restrict__ agg,
    const float* __restrict__ W, float* __restrict__ out, int N)
{
    const int idx = blockIdx.x * 256 + threadIdx.x;
    if (idx >= N * DD) return;
    const int n = idx >> 5;
    const int d = idx & 31;
    const float* arow = agg + (size_t)n * DD;
    float s = h_d[idx];
    #pragma unroll
    for (int k = 0; k < DD; ++k) s = fmaf(arow[k], W[k * DD + d], s);
    out[idx] = s;
}

extern "C" void kernel_launch(void* const* d_in, const int* in_sizes, int n_in,
                              void* d_out, int out_size, void* d_ws, size_t ws_size,
                              hipStream_t stream) {
    const float* h_d = (const float*)d_in[0];
    const float* h_s = (const float*)d_in[1];
    const float* ef  = (const float*)d_in[2];
    const int*   snd = (const int*)d_in[3];
    const int*   rcv = (const int*)d_in[4];
    const float* w0  = (const float*)d_in[5];
    const float* b0  = (const float*)d_in[6];
    const float* w1  = (const float*)d_in[7];
    const float* b1  = (const float*)d_in[8];
    const float* w2  = (const float*)d_in[9];
    const float* b2  = (const float*)d_in[10];
    const float* W   = (const float*)d_in[11];
    float* out = (float*)d_out;

    const int N = in_sizes[0] / DD;
    const int E = in_sizes[3];

    float* agg = (float*)d_ws;  // N*DD floats (12.8 MB) of scratch

    hipMemsetAsync(agg, 0, (size_t)N * DD * sizeof(float), stream);
    edge_kernel<<<(E + 127) / 128, 128, 0, stream>>>(
        h_d, h_s, ef, snd, rcv, w0, b0, w1, b1, w2, b2, agg, E);
    out_kernel<<<((N * DD) + 255) / 256, 256, 0, stream>>>(h_d, agg, W, out, N);
}

// Round 2
// 367.676 us; speedup vs baseline: 4.9475x; 4.9475x over previous
//
#include <hip/hip_runtime.h>

#define DD 32   // node/output dim
#define HH 64   // psi hidden
// PSI_IN = 5*32 = 160

typedef __attribute__((ext_vector_type(8))) short bf16x8;   // 8 bf16 = 4 VGPRs
typedef __attribute__((ext_vector_type(4))) float f32x4;

static __device__ __forceinline__ unsigned short f2bf(float x) {
    // round-to-nearest-even bf16 (inputs are finite; no NaN handling needed)
    union { float f; unsigned u; } v; v.f = x;
    unsigned r = (v.u + 0x7FFFu + ((v.u >> 16) & 1u)) >> 16;
    return (unsigned short)r;
}

// Convert w0/w1/w2 to bf16 MFMA B-fragment order.
// 32 frags total: [0..19] = w0 (kk*4+t), [20..27] = w1 (kk*4+t), [28..31] = w2 (kk*2+t).
// Frag f, lane l (n = t*16 + (l&15), k = kk*32 + (l>>4)*8 + j): 8 bf16 at frags[f*512 + l*8].
__global__ __launch_bounds__(256) void prep_weights(
    const float* __restrict__ w0, const float* __restrict__ w1,
    const float* __restrict__ w2, unsigned short* __restrict__ frags)
{
    const int tid = blockIdx.x * 256 + threadIdx.x;
    const int f = tid >> 6, l = tid & 63;
    if (f >= 32) return;
    const int c = l & 15, q = l >> 4;
    unsigned short* dst = frags + f * 512 + l * 8;
    if (f < 20) {
        const int kk = f >> 2, t = f & 3;
        const int n = t * 16 + c, kb = kk * 32 + q * 8;
        #pragma unroll
        for (int j = 0; j < 8; ++j) dst[j] = f2bf(w0[(kb + j) * HH + n]);
    } else if (f < 28) {
        const int f2 = f - 20, kk = f2 >> 2, t = f2 & 3;
        const int n = t * 16 + c, kb = kk * 32 + q * 8;
        #pragma unroll
        for (int j = 0; j < 8; ++j) dst[j] = f2bf(w1[(kb + j) * HH + n]);
    } else {
        const int f3 = f - 28, kk = f3 >> 1, t = f3 & 1;
        const int n = t * 16 + c, kb = kk * 32 + q * 8;
        #pragma unroll
        for (int j = 0; j < 8; ++j) dst[j] = f2bf(w2[(kb + j) * DD + n]);
    }
}

// One wave per 16-edge tile (grid-stride). 3-layer MLP via mfma_f32_16x16x32_bf16.
// Weights live in 128 VGPRs (32 frags), loaded once per wave.
// Layer-0 A-frags come straight from global gathers (no LDS staging).
// Inter-layer C->A transform via per-wave LDS (stride 72 bf16, 16B-aligned b128 reads).
__global__ __launch_bounds__(256, 2) void edge_mfma(
    const float* __restrict__ h_d, const float* __restrict__ h_s,
    const float* __restrict__ ef,
    const int* __restrict__ snd, const int* __restrict__ rcv,
    const unsigned short* __restrict__ frags,
    const float* __restrict__ b0, const float* __restrict__ b1,
    const float* __restrict__ b2,
    float* __restrict__ agg, int E, int ntiles)
{
    __shared__ __align__(16) unsigned short xbuf[4][2][16 * 72];

    const int lane = threadIdx.x & 63;
    const int w = threadIdx.x >> 6;
    const int c = lane & 15, q = lane >> 4;

    // weight fragments -> registers (32 x 4 VGPRs)
    bf16x8 wf[32];
    #pragma unroll
    for (int f = 0; f < 32; ++f)
        wf[f] = *(const bf16x8*)(frags + f * 512 + lane * 8);

    const float b0t[4] = {b0[c], b0[16 + c], b0[32 + c], b0[48 + c]};
    const float b1t[4] = {b1[c], b1[16 + c], b1[32 + c], b1[48 + c]};
    const float b2t[2] = {b2[c], b2[16 + c]};

    unsigned short* xb1 = xbuf[w][0];
    unsigned short* xb2 = xbuf[w][1];

    const int wave_id = blockIdx.x * 4 + w;
    const int nwaves = gridDim.x * 4;

    for (int tile = wave_id; tile < ntiles; tile += nwaves) {
        const int base = tile * 16;
        int e = base + c; if (e >= E) e = E - 1;   // m = c = lane&15 is the edge row
        const int si = snd[e], ri = rcv[e];
        const float* srcs[5] = { h_s + (size_t)si * DD, h_s + (size_t)ri * DD,
                                 h_d + (size_t)si * DD, h_d + (size_t)ri * DD,
                                 ef  + (size_t)e  * DD };

        // ---- layer 0: [16x160] @ [160x64], A-frags direct from gathers ----
        f32x4 c0[4] = {f32x4{0,0,0,0}, f32x4{0,0,0,0}, f32x4{0,0,0,0}, f32x4{0,0,0,0}};
        #pragma unroll
        for (int kk = 0; kk < 5; ++kk) {
            const float* s = srcs[kk] + q * 8;
            const float4 v0 = ((const float4*)s)[0];
            const float4 v1 = ((const float4*)s)[1];
            bf16x8 a;
            a[0] = (short)f2bf(v0.x); a[1] = (short)f2bf(v0.y);
            a[2] = (short)f2bf(v0.z); a[3] = (short)f2bf(v0.w);
            a[4] = (short)f2bf(v1.x); a[5] = (short)f2bf(v1.y);
            a[6] = (short)f2bf(v1.z); a[7] = (short)f2bf(v1.w);
            #pragma unroll
            for (int t = 0; t < 4; ++t)
                c0[t] = __builtin_amdgcn_mfma_f32_16x16x32_bf16(a, wf[kk * 4 + t], c0[t], 0, 0, 0);
        }
        // relu(C + b0) -> X1 (row = q*4+r, col = t*16+c)
        #pragma unroll
        for (int t = 0; t < 4; ++t) {
            #pragma unroll
            for (int r = 0; r < 4; ++r) {
                const float v = fmaxf(c0[t][r] + b0t[t], 0.0f);
                xb1[(q * 4 + r) * 72 + t * 16 + c] = f2bf(v);
            }
        }

        // ---- layer 1: [16x64] @ [64x64] ----
        f32x4 c1[4] = {f32x4{0,0,0,0}, f32x4{0,0,0,0}, f32x4{0,0,0,0}, f32x4{0,0,0,0}};
        #pragma unroll
        for (int kk = 0; kk < 2; ++kk) {
            const bf16x8 a = *(const bf16x8*)(xb1 + c * 72 + kk * 32 + q * 8);
            #pragma unroll
            for (int t = 0; t < 4; ++t)
                c1[t] = __builtin_amdgcn_mfma_f32_16x16x32_bf16(a, wf[20 + kk * 4 + t], c1[t], 0, 0, 0);
        }
        #pragma unroll
        for (int t = 0; t < 4; ++t) {
            #pragma unroll
            for (int r = 0; r < 4; ++r) {
                const float v = fmaxf(c1[t][r] + b1t[t], 0.0f);
                xb2[(q * 4 + r) * 72 + t * 16 + c] = f2bf(v);
            }
        }

        // ---- layer 2: [16x64] @ [64x32] ----
        f32x4 c2[2] = {f32x4{0,0,0,0}, f32x4{0,0,0,0}};
        #pragma unroll
        for (int kk = 0; kk < 2; ++kk) {
            const bf16x8 a = *(const bf16x8*)(xb2 + c * 72 + kk * 32 + q * 8);
            #pragma unroll
            for (int t = 0; t < 2; ++t)
                c2[t] = __builtin_amdgcn_mfma_f32_16x16x32_bf16(a, wf[28 + kk * 2 + t], c2[t], 0, 0, 0);
        }

        // ---- epilogue: s_ij = relu(psi)*(h_dj - h_di), scatter-add over receivers ----
        int erv[4], sir[4], rir[4];
        #pragma unroll
        for (int r = 0; r < 4; ++r) {
            const int ee = base + q * 4 + r;        // C/D row = edge index
            erv[r] = ee;
            const int eec = ee < E ? ee : E - 1;
            sir[r] = snd[eec]; rir[r] = rcv[eec];
        }
        #pragma unroll
        for (int t = 0; t < 2; ++t) {
            const int h = t * 16 + c;               // C/D col = output dim
            #pragma unroll
            for (int r = 0; r < 4; ++r) {
                if (erv[r] < E) {
                    const float psi = fmaxf(c2[t][r] + b2t[t], 0.0f);
                    const float d = h_d[(size_t)rir[r] * DD + h] - h_d[(size_t)sir[r] * DD + h];
                    atomicAdd(agg + (size_t)rir[r] * DD + h, psi * d);
                }
            }
        }
    }
}

// out[n][d] = h_d_prev[n][d] + sum_k agg[n][k] * W[k][d]
__global__ __launch_bounds__(256) void out_kernel(
    const float* __restrict__ h_d, const float* __restrict__ agg,
    const float* __restrict__ W, float* __restrict__ out, int N)
{
    const int idx = blockIdx.x * 256 + threadIdx.x;
    if (idx >= N * DD) return;
    const int n = idx >> 5;
    const int d = idx & 31;
    const float* arow = agg + (size_t)n * DD;
    float s = h_d[idx];
    #pragma unroll
    for (int k = 0; k < DD; ++k) s = fmaf(arow[k], W[k * DD + d], s);
    out[idx] = s;
}

extern "C" void kernel_launch(void* const* d_in, const int* in_sizes, int n_in,
                              void* d_out, int out_size, void* d_ws, size_t ws_size,
                              hipStream_t stream) {
    const float* h_d = (const float*)d_in[0];
    const float* h_s = (const float*)d_in[1];
    const float* ef  = (const float*)d_in[2];
    const int*   snd = (const int*)d_in[3];
    const int*   rcv = (const int*)d_in[4];
    const float* w0  = (const float*)d_in[5];
    const float* b0  = (const float*)d_in[6];
    const float* w1  = (const float*)d_in[7];
    const float* b1  = (const float*)d_in[8];
    const float* w2  = (const float*)d_in[9];
    const float* b2  = (const float*)d_in[10];
    const float* W   = (const float*)d_in[11];
    float* out = (float*)d_out;

    const int N = in_sizes[0] / DD;
    const int E = in_sizes[3];
    const int ntiles = (E + 15) / 16;

    // d_ws layout: [0, N*DD floats) = agg ; then 32 KB of bf16 weight frags
    float* agg = (float*)d_ws;
    unsigned short* frags = (unsigned short*)((char*)d_ws + (size_t)N * DD * sizeof(float));

    hipMemsetAsync(agg, 0, (size_t)N * DD * sizeof(float), stream);
    prep_weights<<<8, 256, 0, stream>>>(w0, w1, w2, frags);
    edge_mfma<<<1024, 256, 0, stream>>>(h_d, h_s, ef, snd, rcv, frags,
                                        b0, b1, b2, agg, E, ntiles);
    out_kernel<<<((N * DD) + 255) / 256, 256, 0, stream>>>(h_d, agg, W, out, N);
}